// Round 1
// baseline (374.645 us; speedup 1.0000x reference)
//
#include <hip/hip_runtime.h>
#include <hip/hip_bf16.h>
#include <stdint.h>

#define M_DIM 8192
#define N_DIM 4096   // OUT_F
#define K_DIM 4096   // IN_F

#define BM 128
#define BN 128
#define BK 32

typedef __bf16 bf16_t;
typedef __attribute__((ext_vector_type(8))) __bf16 bf16x8;
typedef __attribute__((ext_vector_type(4))) float f32x4;

// ---------------- fp32 -> bf16 convert (vectorized, grid-stride) ----------------
__global__ void cvt_f32_to_bf16(const float* __restrict__ in, bf16_t* __restrict__ out, int n8) {
    int stride = gridDim.x * blockDim.x;
    for (int i = blockIdx.x * blockDim.x + threadIdx.x; i < n8; i += stride) {
        const float4* p = reinterpret_cast<const float4*>(in) + 2 * (size_t)i;
        float4 v0 = p[0];
        float4 v1 = p[1];
        bf16x8 o;
        o[0] = (bf16_t)v0.x; o[1] = (bf16_t)v0.y; o[2] = (bf16_t)v0.z; o[3] = (bf16_t)v0.w;
        o[4] = (bf16_t)v1.x; o[5] = (bf16_t)v1.y; o[6] = (bf16_t)v1.z; o[7] = (bf16_t)v1.w;
        *(reinterpret_cast<bf16x8*>(out) + (size_t)i) = o;
    }
}

// ---------------- bf16 MFMA GEMM, m97 structure (128x128 tile, BK=32) ----------------
// A: [M][K] bf16 row-major; B: [N][K] bf16 row-major (weight is already B^T);
// C: [M][N] fp32. out = A*B^T + bias.
__global__ __launch_bounds__(256) void gemm_bf16_bt(
        const bf16_t* __restrict__ A, const bf16_t* __restrict__ B,
        const float* __restrict__ bias, float* __restrict__ C) {

    __shared__ __align__(16) bf16_t Asm[BM * BK];   // 8 KB, linear (global_load_lds needs linear dest)
    __shared__ __align__(16) bf16_t Bsm[BN * BK];   // 8 KB

    const int tid  = threadIdx.x;
    const int lane = tid & 63;
    const int wave = tid >> 6;        // 0..3
    const int wm   = wave >> 1;       // 0..1 : wave's M half
    const int wn   = wave & 1;        // 0..1 : wave's N half

    // XCD-aware swizzle (nwg = 2048, divisible by 8 -> simple form is bijective)
    const int nwg = gridDim.x;
    const int cpx = nwg >> 3;
    const int swz = (blockIdx.x & 7) * cpx + (blockIdx.x >> 3);
    const int ntn = N_DIM / BN;       // 32
    const int tm  = swz / ntn;
    const int tn  = swz % ntn;
    const int brow = tm * BM;
    const int bcol = tn * BN;

    f32x4 acc[4][4];
#pragma unroll
    for (int i = 0; i < 4; i++)
#pragma unroll
        for (int j = 0; j < 4; j++)
            acc[i][j] = (f32x4){0.f, 0.f, 0.f, 0.f};

    // Staging decomposition: tile = 128 rows x 32 cols bf16 = 8192 B = 512 chunks of 16 B.
    // chunk c covers LDS bytes [c*16, c*16+16) == row (c>>2), elems ((c&3)*8 .. +8).
    // Wave w, issue j owns chunks [(j*4+w)*64 .. +64); HW dest = wave-uniform base + lane*16.
    const int c0 = wave * 64 + lane;          // issue-0 chunk for this lane
    const int c1 = c0 + 256;                  // issue-1 chunk
    const int r0 = c0 >> 2, q0 = (c0 & 3) * 8;
    const int r1 = c1 >> 2, q1 = (c1 & 3) * 8;

    const bf16_t* Ab = A + (size_t)brow * K_DIM;
    const bf16_t* Bb = B + (size_t)bcol * K_DIM;

    // MFMA fragment addressing (16x16x32 bf16): lane holds row (lane&15), k = (lane>>4)*8 .. +8
    const int fr = lane & 15;
    const int fk = (lane >> 4) * 8;

    for (int k0 = 0; k0 < K_DIM; k0 += BK) {
        // ---- stage A tile ----
        __builtin_amdgcn_global_load_lds(
            (const __attribute__((address_space(1))) void*)(Ab + (size_t)r0 * K_DIM + k0 + q0),
            (__attribute__((address_space(3))) void*)(&Asm[wave * 512]), 16, 0, 0);
        __builtin_amdgcn_global_load_lds(
            (const __attribute__((address_space(1))) void*)(Ab + (size_t)r1 * K_DIM + k0 + q1),
            (__attribute__((address_space(3))) void*)(&Asm[(4 + wave) * 512]), 16, 0, 0);
        // ---- stage B tile ----
        __builtin_amdgcn_global_load_lds(
            (const __attribute__((address_space(1))) void*)(Bb + (size_t)r0 * K_DIM + k0 + q0),
            (__attribute__((address_space(3))) void*)(&Bsm[wave * 512]), 16, 0, 0);
        __builtin_amdgcn_global_load_lds(
            (const __attribute__((address_space(1))) void*)(Bb + (size_t)r1 * K_DIM + k0 + q1),
            (__attribute__((address_space(3))) void*)(&Bsm[(4 + wave) * 512]), 16, 0, 0);

        __syncthreads();

        bf16x8 af[4], bfr[4];
#pragma unroll
        for (int mi = 0; mi < 4; mi++)
            af[mi] = *reinterpret_cast<const bf16x8*>(&Asm[(wm * 64 + mi * 16 + fr) * BK + fk]);
#pragma unroll
        for (int ni = 0; ni < 4; ni++)
            bfr[ni] = *reinterpret_cast<const bf16x8*>(&Bsm[(wn * 64 + ni * 16 + fr) * BK + fk]);

#pragma unroll
        for (int mi = 0; mi < 4; mi++)
#pragma unroll
            for (int ni = 0; ni < 4; ni++)
                acc[mi][ni] = __builtin_amdgcn_mfma_f32_16x16x32_bf16(af[mi], bfr[ni], acc[mi][ni], 0, 0, 0);

        __syncthreads();
    }

    // ---- epilogue: C/D layout col = lane&15, row = (lane>>4)*4 + r ----
    const int cc0 = bcol + wn * 64 + (lane & 15);
    const int rr0 = brow + wm * 64 + (lane >> 4) * 4;

    float bv[4];
#pragma unroll
    for (int ni = 0; ni < 4; ni++) bv[ni] = bias[cc0 + ni * 16];

#pragma unroll
    for (int mi = 0; mi < 4; mi++) {
#pragma unroll
        for (int r = 0; r < 4; r++) {
            const size_t row = (size_t)(rr0 + mi * 16 + r);
#pragma unroll
            for (int ni = 0; ni < 4; ni++) {
                C[row * N_DIM + cc0 + ni * 16] = acc[mi][ni][r] + bv[ni];
            }
        }
    }
}

// ---------------- safety-net fallback (no workspace): plain fp32 dot ----------------
__global__ void gemm_fallback_f32(const float* __restrict__ A, const float* __restrict__ B,
                                  const float* __restrict__ bias, float* __restrict__ C) {
    int n = blockIdx.x * 16 + threadIdx.x;
    int m = blockIdx.y * 16 + threadIdx.y;
    if (m >= M_DIM || n >= N_DIM) return;
    const float4* a = reinterpret_cast<const float4*>(A + (size_t)m * K_DIM);
    const float4* b = reinterpret_cast<const float4*>(B + (size_t)n * K_DIM);
    float s = 0.f;
    for (int k = 0; k < K_DIM / 4; k++) {
        float4 x = a[k], y = b[k];
        s += x.x * y.x + x.y * y.y + x.z * y.z + x.w * y.w;
    }
    C[(size_t)m * N_DIM + n] = s + bias[n];
}

extern "C" void kernel_launch(void* const* d_in, const int* in_sizes, int n_in,
                              void* d_out, int out_size, void* d_ws, size_t ws_size,
                              hipStream_t stream) {
    const float* x    = (const float*)d_in[0];   // [M][K] fp32
    const float* w    = (const float*)d_in[1];   // [N][K] fp32 (already B^T layout)
    const float* bias = (const float*)d_in[2];   // [N] fp32
    float* out = (float*)d_out;

    const size_t xb = (size_t)M_DIM * K_DIM * sizeof(bf16_t);   // 64 MB
    const size_t wb = (size_t)N_DIM * K_DIM * sizeof(bf16_t);   // 32 MB

    if (ws_size >= xb + wb) {
        bf16_t* xbf = (bf16_t*)d_ws;
        bf16_t* wbf = (bf16_t*)((char*)d_ws + xb);

        cvt_f32_to_bf16<<<2048, 256, 0, stream>>>(x, xbf, (M_DIM * K_DIM) / 8);
        cvt_f32_to_bf16<<<1024, 256, 0, stream>>>(w, wbf, (N_DIM * K_DIM) / 8);

        const int grid = (M_DIM / BM) * (N_DIM / BN);   // 64 * 32 = 2048
        gemm_bf16_bt<<<grid, 256, 0, stream>>>(xbf, wbf, bias, out);
    } else {
        dim3 block(16, 16);
        dim3 grid(N_DIM / 16, M_DIM / 16);
        gemm_fallback_f32<<<grid, block, 0, stream>>>(x, w, bias, out);
    }
}

// Round 2
// 292.812 us; speedup vs baseline: 1.2795x; 1.2795x over previous
//
#include <hip/hip_runtime.h>
#include <hip/hip_bf16.h>
#include <stdint.h>

#define M_DIM 8192
#define N_DIM 4096   // OUT_F
#define K_DIM 4096   // IN_F

#define BM 256
#define BN 256
#define BK 32
#define NT (K_DIM / BK)   // 128 K-tiles
#define NBUF 4

typedef __bf16 bf16_t;
typedef __attribute__((ext_vector_type(8))) __bf16 bf16x8;
typedef __attribute__((ext_vector_type(4))) float f32x4;

// ---------------- fp32 -> bf16 convert (vectorized, grid-stride) ----------------
__global__ void cvt_f32_to_bf16(const float* __restrict__ in, bf16_t* __restrict__ out, int n8) {
    int stride = gridDim.x * blockDim.x;
    for (int i = blockIdx.x * blockDim.x + threadIdx.x; i < n8; i += stride) {
        const float4* p = reinterpret_cast<const float4*>(in) + 2 * (size_t)i;
        float4 v0 = p[0];
        float4 v1 = p[1];
        bf16x8 o;
        o[0] = (bf16_t)v0.x; o[1] = (bf16_t)v0.y; o[2] = (bf16_t)v0.z; o[3] = (bf16_t)v0.w;
        o[4] = (bf16_t)v1.x; o[5] = (bf16_t)v1.y; o[6] = (bf16_t)v1.z; o[7] = (bf16_t)v1.w;
        *(reinterpret_cast<bf16x8*>(out) + (size_t)i) = o;
    }
}

// ---------------- 256x256 deep-pipelined bf16 MFMA GEMM ----------------
// A: [M][K] bf16 row-major; B: [N][K] bf16 row-major (weight = B^T layout);
// C = A*B^T + bias, fp32 out.
//
// 4-deep LDS K-tile ring (BK=32): compute tile t from buf[t%4] while tile t+3
// stages into buf[(t+3)%4] (= buf[(t-1)%4], whose reads finished last tile ->
// race-free by barrier ordering). vmcnt(8) once per tile keeps 2 tiles (8 loads)
// in flight. T2 XOR swizzle (cc ^= (row>>1)&3, involution) applied to the
// global source of global_load_lds (linear LDS dest) and to ds_read addrs.

#define MF(a, b, c) __builtin_amdgcn_mfma_f32_16x16x32_bf16((a), (b), (c), 0, 0, 0)

#define STAGE_A(T) {                                                                  \
    const int sb_ = (T) & 3; const size_t kof_ = (size_t)(T) * BK;                    \
    __builtin_amdgcn_global_load_lds(                                                 \
        (const __attribute__((address_space(1))) void*)(gA0 + kof_),                  \
        (__attribute__((address_space(3))) void*)(&smem[sb_][0][dst0]), 16, 0, 0);    \
    __builtin_amdgcn_global_load_lds(                                                 \
        (const __attribute__((address_space(1))) void*)(gA1 + kof_),                  \
        (__attribute__((address_space(3))) void*)(&smem[sb_][0][dst1]), 16, 0, 0);    \
}

#define STAGE_B(T) {                                                                  \
    const int sb_ = (T) & 3; const size_t kof_ = (size_t)(T) * BK;                    \
    __builtin_amdgcn_global_load_lds(                                                 \
        (const __attribute__((address_space(1))) void*)(gB0 + kof_),                  \
        (__attribute__((address_space(3))) void*)(&smem[sb_][1][dst0]), 16, 0, 0);    \
    __builtin_amdgcn_global_load_lds(                                                 \
        (const __attribute__((address_space(1))) void*)(gB1 + kof_),                  \
        (__attribute__((address_space(3))) void*)(&smem[sb_][1][dst1]), 16, 0, 0);    \
}

#define TILE(T, STG, VMSTR) do {                                                      \
    bf16_t* Al_ = &smem[(T) & 3][0][0];                                               \
    bf16_t* Bl_ = &smem[(T) & 3][1][0];                                               \
    /* phase 0: ds_read A rows [wm*128, +64) + all B frags; stage A(t+3) */           \
    bf16x8 a0_ = *(const bf16x8*)(Al_ + oa0);                                         \
    bf16x8 a1_ = *(const bf16x8*)(Al_ + oa1);                                         \
    bf16x8 a2_ = *(const bf16x8*)(Al_ + oa2);                                         \
    bf16x8 a3_ = *(const bf16x8*)(Al_ + oa3);                                         \
    bf16x8 b0_ = *(const bf16x8*)(Bl_ + ob0);                                         \
    bf16x8 b1_ = *(const bf16x8*)(Bl_ + ob1);                                         \
    bf16x8 b2_ = *(const bf16x8*)(Bl_ + ob2);                                         \
    bf16x8 b3_ = *(const bf16x8*)(Bl_ + ob3);                                         \
    if (STG) STAGE_A((T) + 3);                                                        \
    __builtin_amdgcn_s_barrier();                                                     \
    __builtin_amdgcn_s_setprio(1);                                                    \
    acc[0][0] = MF(a0_, b0_, acc[0][0]); acc[0][1] = MF(a0_, b1_, acc[0][1]);         \
    acc[0][2] = MF(a0_, b2_, acc[0][2]); acc[0][3] = MF(a0_, b3_, acc[0][3]);         \
    acc[1][0] = MF(a1_, b0_, acc[1][0]); acc[1][1] = MF(a1_, b1_, acc[1][1]);         \
    acc[1][2] = MF(a1_, b2_, acc[1][2]); acc[1][3] = MF(a1_, b3_, acc[1][3]);         \
    acc[2][0] = MF(a2_, b0_, acc[2][0]); acc[2][1] = MF(a2_, b1_, acc[2][1]);         \
    acc[2][2] = MF(a2_, b2_, acc[2][2]); acc[2][3] = MF(a2_, b3_, acc[2][3]);         \
    acc[3][0] = MF(a3_, b0_, acc[3][0]); acc[3][1] = MF(a3_, b1_, acc[3][1]);         \
    acc[3][2] = MF(a3_, b2_, acc[3][2]); acc[3][3] = MF(a3_, b3_, acc[3][3]);         \
    __builtin_amdgcn_s_setprio(0);                                                    \
    __builtin_amdgcn_s_barrier();                                                     \
    /* phase 1: ds_read A rows [wm*128+64, +64); B reused in regs; stage B(t+3) */    \
    bf16x8 a4_ = *(const bf16x8*)(Al_ + oa4);                                         \
    bf16x8 a5_ = *(const bf16x8*)(Al_ + oa5);                                         \
    bf16x8 a6_ = *(const bf16x8*)(Al_ + oa6);                                         \
    bf16x8 a7_ = *(const bf16x8*)(Al_ + oa7);                                         \
    if (STG) STAGE_B((T) + 3);                                                        \
    __builtin_amdgcn_s_barrier();                                                     \
    __builtin_amdgcn_s_setprio(1);                                                    \
    acc[4][0] = MF(a4_, b0_, acc[4][0]); acc[4][1] = MF(a4_, b1_, acc[4][1]);         \
    acc[4][2] = MF(a4_, b2_, acc[4][2]); acc[4][3] = MF(a4_, b3_, acc[4][3]);         \
    acc[5][0] = MF(a5_, b0_, acc[5][0]); acc[5][1] = MF(a5_, b1_, acc[5][1]);         \
    acc[5][2] = MF(a5_, b2_, acc[5][2]); acc[5][3] = MF(a5_, b3_, acc[5][3]);         \
    acc[6][0] = MF(a6_, b0_, acc[6][0]); acc[6][1] = MF(a6_, b1_, acc[6][1]);         \
    acc[6][2] = MF(a6_, b2_, acc[6][2]); acc[6][3] = MF(a6_, b3_, acc[6][3]);         \
    acc[7][0] = MF(a7_, b0_, acc[7][0]); acc[7][1] = MF(a7_, b1_, acc[7][1]);         \
    acc[7][2] = MF(a7_, b2_, acc[7][2]); acc[7][3] = MF(a7_, b3_, acc[7][3]);         \
    __builtin_amdgcn_s_setprio(0);                                                    \
    asm volatile(VMSTR ::: "memory");                                                 \
    __builtin_amdgcn_s_barrier();                                                     \
} while (0)

__global__ __launch_bounds__(512, 2) void gemm_bf16_8phase(
        const bf16_t* __restrict__ A, const bf16_t* __restrict__ B,
        const float* __restrict__ bias, float* __restrict__ C) {

    __shared__ __align__(16) bf16_t smem[NBUF][2][BM * BK];   // 4 x (A,B) x 16KB = 128 KiB

    const int tid  = threadIdx.x;
    const int lane = tid & 63;
    const int wave = tid >> 6;        // 0..7
    const int wm   = wave >> 2;       // 0..1 : M half (128 rows)
    const int wn   = wave & 3;        // 0..3 : N quarter (64 cols)

    // XCD-aware swizzle (nwg = 512, divisible by 8 -> bijective)
    const int nwg = gridDim.x;
    const int cpx = nwg >> 3;
    const int swz = (blockIdx.x & 7) * cpx + (blockIdx.x >> 3);
    const int ntn = N_DIM / BN;       // 16
    const int brow = (swz / ntn) * BM;
    const int bcol = (swz % ntn) * BN;

    // ---- staging geometry: tile (A or B) = 256 rows x 32 bf16 = 16KB = 1024 x 16B chunks.
    // slot s holds global (row = s>>2, cc = (s&3) ^ ((s>>3)&3))  [involution swizzle].
    const int slot0 = wave * 128 + lane;
    const int slot1 = slot0 + 64;
    const int r0 = slot0 >> 2, c0 = ((slot0 & 3) ^ ((slot0 >> 3) & 3)) << 3;
    const int r1 = slot1 >> 2, c1 = ((slot1 & 3) ^ ((slot1 >> 3) & 3)) << 3;
    const bf16_t* gA0 = A + (size_t)(brow + r0) * K_DIM + c0;
    const bf16_t* gA1 = A + (size_t)(brow + r1) * K_DIM + c1;
    const bf16_t* gB0 = B + (size_t)(bcol + r0) * K_DIM + c0;
    const bf16_t* gB1 = B + (size_t)(bcol + r1) * K_DIM + c1;
    const int dst0 = wave * 1024;     // elem offset (slot * 8)
    const int dst1 = dst0 + 512;

    // ---- ds_read fragment offsets (elems), swizzled to match staging
    const int fr = lane & 15;
    const int cc = lane >> 4;         // k-chunk 0..3 (k = cc*8)
#define AOFF(p, mi) ({ int row_ = wm*128 + (p)*64 + (mi)*16 + fr; \
                       row_*32 + ((cc ^ ((row_ >> 1) & 3)) << 3); })
#define BOFF(ni)    ({ int row_ = wn*64 + (ni)*16 + fr; \
                       row_*32 + ((cc ^ ((row_ >> 1) & 3)) << 3); })
    const int oa0 = AOFF(0,0), oa1 = AOFF(0,1), oa2 = AOFF(0,2), oa3 = AOFF(0,3);
    const int oa4 = AOFF(1,0), oa5 = AOFF(1,1), oa6 = AOFF(1,2), oa7 = AOFF(1,3);
    const int ob0 = BOFF(0), ob1 = BOFF(1), ob2 = BOFF(2), ob3 = BOFF(3);

    f32x4 acc[8][4];
#pragma unroll
    for (int i = 0; i < 8; i++)
#pragma unroll
        for (int j = 0; j < 4; j++)
            acc[i][j] = (f32x4){0.f, 0.f, 0.f, 0.f};

    // ---- prologue: stage tiles 0,1,2; land tile 0; keep 8 loads (tiles 1,2) in flight
    STAGE_A(0) STAGE_B(0)
    STAGE_A(1) STAGE_B(1)
    STAGE_A(2) STAGE_B(2)
    asm volatile("s_waitcnt vmcnt(8)" ::: "memory");
    __builtin_amdgcn_s_barrier();

    // ---- main loop: steady state vmcnt(8); epilogue drains 8 -> 4 -> 0
    for (int t = 0; t < NT - 3; ++t)
        TILE(t, 1, "s_waitcnt vmcnt(8)");
    TILE(NT - 3, 0, "s_waitcnt vmcnt(4)");
    TILE(NT - 2, 0, "s_waitcnt vmcnt(0)");
    TILE(NT - 1, 0, "");

    // ---- epilogue: C/D layout col = lane&15, row = (lane>>4)*4 + r
    const int cc0 = bcol + wn * 64 + (lane & 15);
    const int rr0 = brow + wm * 128 + (lane >> 4) * 4;

    float bv[4];
#pragma unroll
    for (int ni = 0; ni < 4; ni++) bv[ni] = bias[cc0 + ni * 16];

#pragma unroll
    for (int p = 0; p < 2; p++) {
#pragma unroll
        for (int i = 0; i < 4; i++) {
#pragma unroll
            for (int r = 0; r < 4; r++) {
                const size_t row = (size_t)(rr0 + p * 64 + i * 16 + r);
#pragma unroll
                for (int ni = 0; ni < 4; ni++) {
                    C[row * N_DIM + cc0 + ni * 16] = acc[p * 4 + i][ni][r] + bv[ni];
                }
            }
        }
    }
}

// ---------------- safety-net fallback (no workspace): plain fp32 dot ----------------
__global__ void gemm_fallback_f32(const float* __restrict__ A, const float* __restrict__ B,
                                  const float* __restrict__ bias, float* __restrict__ C) {
    int n = blockIdx.x * 16 + threadIdx.x;
    int m = blockIdx.y * 16 + threadIdx.y;
    if (m >= M_DIM || n >= N_DIM) return;
    const float4* a = reinterpret_cast<const float4*>(A + (size_t)m * K_DIM);
    const float4* b = reinterpret_cast<const float4*>(B + (size_t)n * K_DIM);
    float s = 0.f;
    for (int k = 0; k < K_DIM / 4; k++) {
        float4 x = a[k], y = b[k];
        s += x.x * y.x + x.y * y.y + x.z * y.z + x.w * y.w;
    }
    C[(size_t)m * N_DIM + n] = s + bias[n];
}

extern "C" void kernel_launch(void* const* d_in, const int* in_sizes, int n_in,
                              void* d_out, int out_size, void* d_ws, size_t ws_size,
                              hipStream_t stream) {
    const float* x    = (const float*)d_in[0];   // [M][K] fp32
    const float* w    = (const float*)d_in[1];   // [N][K] fp32 (B^T layout)
    const float* bias = (const float*)d_in[2];   // [N] fp32
    float* out = (float*)d_out;

    const size_t xb = (size_t)M_DIM * K_DIM * sizeof(bf16_t);   // 64 MB
    const size_t wb = (size_t)N_DIM * K_DIM * sizeof(bf16_t);   // 32 MB

    if (ws_size >= xb + wb) {
        bf16_t* xbf = (bf16_t*)d_ws;
        bf16_t* wbf = (bf16_t*)((char*)d_ws + xb);

        cvt_f32_to_bf16<<<2048, 256, 0, stream>>>(x, xbf, (M_DIM * K_DIM) / 8);
        cvt_f32_to_bf16<<<1024, 256, 0, stream>>>(w, wbf, (N_DIM * K_DIM) / 8);

        const int grid = (M_DIM / BM) * (N_DIM / BN);   // 32 * 16 = 512
        gemm_bf16_8phase<<<grid, 512, 0, stream>>>(xbf, wbf, bias, out);
    } else {
        dim3 block(16, 16);
        dim3 grid(N_DIM / 16, M_DIM / 16);
        gemm_fallback_f32<<<grid, block, 0, stream>>>(x, w, bias, out);
    }
}

// Round 3
// 288.142 us; speedup vs baseline: 1.3002x; 1.0162x over previous
//
#include <hip/hip_runtime.h>
#include <hip/hip_bf16.h>
#include <stdint.h>

#define M_DIM 8192
#define N_DIM 4096   // OUT_F
#define K_DIM 4096   // IN_F

#define BM 256
#define BN 256
#define BK 32
#define NT (K_DIM / BK)   // 128 K-tiles
#define NBUF 4

typedef __bf16 bf16_t;
typedef __attribute__((ext_vector_type(8))) __bf16 bf16x8;
typedef __attribute__((ext_vector_type(4))) float f32x4;

// ---------------- fp32 -> bf16 convert (vectorized, grid-stride) ----------------
__global__ void cvt_f32_to_bf16(const float* __restrict__ in, bf16_t* __restrict__ out, int n8) {
    int stride = gridDim.x * blockDim.x;
    for (int i = blockIdx.x * blockDim.x + threadIdx.x; i < n8; i += stride) {
        const float4* p = reinterpret_cast<const float4*>(in) + 2 * (size_t)i;
        float4 v0 = p[0];
        float4 v1 = p[1];
        bf16x8 o;
        o[0] = (bf16_t)v0.x; o[1] = (bf16_t)v0.y; o[2] = (bf16_t)v0.z; o[3] = (bf16_t)v0.w;
        o[4] = (bf16_t)v1.x; o[5] = (bf16_t)v1.y; o[6] = (bf16_t)v1.z; o[7] = (bf16_t)v1.w;
        *(reinterpret_cast<bf16x8*>(out) + (size_t)i) = o;
    }
}

// ---------------- 256x256 deep-pipelined bf16 MFMA GEMM, barrier-light ----------------
// A: [M][K] bf16 row-major; B: [N][K] bf16 row-major (weight = B^T layout);
// C = A*B^T + bias, fp32 out.
//
// 4-deep LDS K-tile ring (BK=32). ONE barrier + ONE counted vmcnt per K-tile:
//   - WAR: STAGE(T+3) writes buf[(T-1)&3]; all reads of that buffer were consumed
//     by MFMAs (in-wave lgkmcnt) before tile T-1's final barrier.
//   - RAW: vmcnt(8) at end of tile T drains the 4 oldest loads = tile T+1's, and
//     the final barrier publishes that to all waves before tile T+1's reads.
// No inner barriers -> waves slip within a tile; ds_read of one wave overlaps
// MFMA of the other wave on the same SIMD. setprio wraps the pure-MFMA clusters.

#define MF(a, b, c) __builtin_amdgcn_mfma_f32_16x16x32_bf16((a), (b), (c), 0, 0, 0)

#define STAGE_A(T) {                                                                  \
    const int sb_ = (T) & 3; const size_t kof_ = (size_t)(T) * BK;                    \
    __builtin_amdgcn_global_load_lds(                                                 \
        (const __attribute__((address_space(1))) void*)(gA0 + kof_),                  \
        (__attribute__((address_space(3))) void*)(&smem[sb_][0][dst0]), 16, 0, 0);    \
    __builtin_amdgcn_global_load_lds(                                                 \
        (const __attribute__((address_space(1))) void*)(gA1 + kof_),                  \
        (__attribute__((address_space(3))) void*)(&smem[sb_][0][dst1]), 16, 0, 0);    \
}

#define STAGE_B(T) {                                                                  \
    const int sb_ = (T) & 3; const size_t kof_ = (size_t)(T) * BK;                    \
    __builtin_amdgcn_global_load_lds(                                                 \
        (const __attribute__((address_space(1))) void*)(gB0 + kof_),                  \
        (__attribute__((address_space(3))) void*)(&smem[sb_][1][dst0]), 16, 0, 0);    \
    __builtin_amdgcn_global_load_lds(                                                 \
        (const __attribute__((address_space(1))) void*)(gB1 + kof_),                  \
        (__attribute__((address_space(3))) void*)(&smem[sb_][1][dst1]), 16, 0, 0);    \
}

#define TILE(T, STG, VMSTR) do {                                                      \
    bf16_t* Al_ = &smem[(T) & 3][0][0];                                               \
    bf16_t* Bl_ = &smem[(T) & 3][1][0];                                               \
    /* issue ALL memory first: 12 ds_read + 4 global_load_lds */                      \
    bf16x8 a0_ = *(const bf16x8*)(Al_ + oa0);                                         \
    bf16x8 a1_ = *(const bf16x8*)(Al_ + oa1);                                         \
    bf16x8 a2_ = *(const bf16x8*)(Al_ + oa2);                                         \
    bf16x8 a3_ = *(const bf16x8*)(Al_ + oa3);                                         \
    bf16x8 b0_ = *(const bf16x8*)(Bl_ + ob0);                                         \
    bf16x8 b1_ = *(const bf16x8*)(Bl_ + ob1);                                         \
    bf16x8 b2_ = *(const bf16x8*)(Bl_ + ob2);                                         \
    bf16x8 b3_ = *(const bf16x8*)(Bl_ + ob3);                                         \
    if (STG) STAGE_A((T) + 3);                                                        \
    bf16x8 a4_ = *(const bf16x8*)(Al_ + oa4);                                         \
    bf16x8 a5_ = *(const bf16x8*)(Al_ + oa5);                                         \
    bf16x8 a6_ = *(const bf16x8*)(Al_ + oa6);                                         \
    bf16x8 a7_ = *(const bf16x8*)(Al_ + oa7);                                         \
    if (STG) STAGE_B((T) + 3);                                                        \
    /* MFMA cluster 1 (acc rows 0-3): needs a0-a3,b0-b3 only -> fine lgkmcnt */       \
    __builtin_amdgcn_s_setprio(1);                                                    \
    acc[0][0] = MF(a0_, b0_, acc[0][0]); acc[0][1] = MF(a0_, b1_, acc[0][1]);         \
    acc[0][2] = MF(a0_, b2_, acc[0][2]); acc[0][3] = MF(a0_, b3_, acc[0][3]);         \
    acc[1][0] = MF(a1_, b0_, acc[1][0]); acc[1][1] = MF(a1_, b1_, acc[1][1]);         \
    acc[1][2] = MF(a1_, b2_, acc[1][2]); acc[1][3] = MF(a1_, b3_, acc[1][3]);         \
    acc[2][0] = MF(a2_, b0_, acc[2][0]); acc[2][1] = MF(a2_, b1_, acc[2][1]);         \
    acc[2][2] = MF(a2_, b2_, acc[2][2]); acc[2][3] = MF(a2_, b3_, acc[2][3]);         \
    acc[3][0] = MF(a3_, b0_, acc[3][0]); acc[3][1] = MF(a3_, b1_, acc[3][1]);         \
    acc[3][2] = MF(a3_, b2_, acc[3][2]); acc[3][3] = MF(a3_, b3_, acc[3][3]);         \
    __builtin_amdgcn_s_setprio(0);                                                    \
    /* MFMA cluster 2 (acc rows 4-7): needs a4-a7 */                                  \
    __builtin_amdgcn_s_setprio(1);                                                    \
    acc[4][0] = MF(a4_, b0_, acc[4][0]); acc[4][1] = MF(a4_, b1_, acc[4][1]);         \
    acc[4][2] = MF(a4_, b2_, acc[4][2]); acc[4][3] = MF(a4_, b3_, acc[4][3]);         \
    acc[5][0] = MF(a5_, b0_, acc[5][0]); acc[5][1] = MF(a5_, b1_, acc[5][1]);         \
    acc[5][2] = MF(a5_, b2_, acc[5][2]); acc[5][3] = MF(a5_, b3_, acc[5][3]);         \
    acc[6][0] = MF(a6_, b0_, acc[6][0]); acc[6][1] = MF(a6_, b1_, acc[6][1]);         \
    acc[6][2] = MF(a6_, b2_, acc[6][2]); acc[6][3] = MF(a6_, b3_, acc[6][3]);         \
    acc[7][0] = MF(a7_, b0_, acc[7][0]); acc[7][1] = MF(a7_, b1_, acc[7][1]);         \
    acc[7][2] = MF(a7_, b2_, acc[7][2]); acc[7][3] = MF(a7_, b3_, acc[7][3]);         \
    __builtin_amdgcn_s_setprio(0);                                                    \
    asm volatile(VMSTR ::: "memory");                                                 \
    __builtin_amdgcn_s_barrier();                                                     \
} while (0)

__global__ __launch_bounds__(512, 2) void gemm_bf16_8phase(
        const bf16_t* __restrict__ A, const bf16_t* __restrict__ B,
        const float* __restrict__ bias, float* __restrict__ C) {

    __shared__ __align__(16) bf16_t smem[NBUF][2][BM * BK];   // 4 x (A,B) x 16KB = 128 KiB

    const int tid  = threadIdx.x;
    const int lane = tid & 63;
    const int wave = tid >> 6;        // 0..7
    const int wm   = wave >> 2;       // 0..1 : M half (128 rows)
    const int wn   = wave & 3;        // 0..3 : N quarter (64 cols)

    // XCD-aware swizzle (nwg = 512, divisible by 8 -> bijective)
    const int nwg = gridDim.x;
    const int cpx = nwg >> 3;
    const int swz = (blockIdx.x & 7) * cpx + (blockIdx.x >> 3);
    const int ntn = N_DIM / BN;       // 16
    const int brow = (swz / ntn) * BM;
    const int bcol = (swz % ntn) * BN;

    // ---- staging geometry: tile (A or B) = 256 rows x 32 bf16 = 16KB = 1024 x 16B chunks.
    // slot s holds global (row = s>>2, cc = (s&3) ^ ((s>>3)&3))  [involution swizzle].
    const int slot0 = wave * 128 + lane;
    const int slot1 = slot0 + 64;
    const int r0 = slot0 >> 2, c0 = ((slot0 & 3) ^ ((slot0 >> 3) & 3)) << 3;
    const int r1 = slot1 >> 2, c1 = ((slot1 & 3) ^ ((slot1 >> 3) & 3)) << 3;
    const bf16_t* gA0 = A + (size_t)(brow + r0) * K_DIM + c0;
    const bf16_t* gA1 = A + (size_t)(brow + r1) * K_DIM + c1;
    const bf16_t* gB0 = B + (size_t)(bcol + r0) * K_DIM + c0;
    const bf16_t* gB1 = B + (size_t)(bcol + r1) * K_DIM + c1;
    const int dst0 = wave * 1024;     // elem offset (slot * 8)
    const int dst1 = dst0 + 512;

    // ---- ds_read fragment offsets (elems), swizzled to match staging
    const int fr = lane & 15;
    const int cc = lane >> 4;         // k-chunk 0..3 (k = cc*8)
#define AOFF(p, mi) ({ int row_ = wm*128 + (p)*64 + (mi)*16 + fr; \
                       row_*32 + ((cc ^ ((row_ >> 1) & 3)) << 3); })
#define BOFF(ni)    ({ int row_ = wn*64 + (ni)*16 + fr; \
                       row_*32 + ((cc ^ ((row_ >> 1) & 3)) << 3); })
    const int oa0 = AOFF(0,0), oa1 = AOFF(0,1), oa2 = AOFF(0,2), oa3 = AOFF(0,3);
    const int oa4 = AOFF(1,0), oa5 = AOFF(1,1), oa6 = AOFF(1,2), oa7 = AOFF(1,3);
    const int ob0 = BOFF(0), ob1 = BOFF(1), ob2 = BOFF(2), ob3 = BOFF(3);

    f32x4 acc[8][4];
#pragma unroll
    for (int i = 0; i < 8; i++)
#pragma unroll
        for (int j = 0; j < 4; j++)
            acc[i][j] = (f32x4){0.f, 0.f, 0.f, 0.f};

    // ---- prologue: stage tiles 0,1,2; land tile 0; keep 8 loads (tiles 1,2) in flight
    STAGE_A(0) STAGE_B(0)
    STAGE_A(1) STAGE_B(1)
    STAGE_A(2) STAGE_B(2)
    asm volatile("s_waitcnt vmcnt(8)" ::: "memory");
    __builtin_amdgcn_s_barrier();

    // ---- main loop: steady state vmcnt(8); epilogue drains 8 -> 4 -> 0
    for (int t = 0; t < NT - 3; ++t)
        TILE(t, 1, "s_waitcnt vmcnt(8)");
    TILE(NT - 3, 0, "s_waitcnt vmcnt(4)");
    TILE(NT - 2, 0, "s_waitcnt vmcnt(0)");
    TILE(NT - 1, 0, "s_nop 0");

    // ---- epilogue: C/D layout col = lane&15, row = (lane>>4)*4 + r
    const int cc0 = bcol + wn * 64 + (lane & 15);
    const int rr0 = brow + wm * 128 + (lane >> 4) * 4;

    float bv[4];
#pragma unroll
    for (int ni = 0; ni < 4; ni++) bv[ni] = bias[cc0 + ni * 16];

#pragma unroll
    for (int p = 0; p < 2; p++) {
#pragma unroll
        for (int i = 0; i < 4; i++) {
#pragma unroll
            for (int r = 0; r < 4; r++) {
                const size_t row = (size_t)(rr0 + p * 64 + i * 16 + r);
#pragma unroll
                for (int ni = 0; ni < 4; ni++) {
                    C[row * N_DIM + cc0 + ni * 16] = acc[p * 4 + i][ni][r] + bv[ni];
                }
            }
        }
    }
}

// ---------------- safety-net fallback (no workspace): plain fp32 dot ----------------
__global__ void gemm_fallback_f32(const float* __restrict__ A, const float* __restrict__ B,
                                  const float* __restrict__ bias, float* __restrict__ C) {
    int n = blockIdx.x * 16 + threadIdx.x;
    int m = blockIdx.y * 16 + threadIdx.y;
    if (m >= M_DIM || n >= N_DIM) return;
    const float4* a = reinterpret_cast<const float4*>(A + (size_t)m * K_DIM);
    const float4* b = reinterpret_cast<const float4*>(B + (size_t)n * K_DIM);
    float s = 0.f;
    for (int k = 0; k < K_DIM / 4; k++) {
        float4 x = a[k], y = b[k];
        s += x.x * y.x + x.y * y.y + x.z * y.z + x.w * y.w;
    }
    C[(size_t)m * N_DIM + n] = s + bias[n];
}

extern "C" void kernel_launch(void* const* d_in, const int* in_sizes, int n_in,
                              void* d_out, int out_size, void* d_ws, size_t ws_size,
                              hipStream_t stream) {
    const float* x    = (const float*)d_in[0];   // [M][K] fp32
    const float* w    = (const float*)d_in[1];   // [N][K] fp32 (B^T layout)
    const float* bias = (const float*)d_in[2];   // [N] fp32
    float* out = (float*)d_out;

    const size_t xb = (size_t)M_DIM * K_DIM * sizeof(bf16_t);   // 64 MB
    const size_t wb = (size_t)N_DIM * K_DIM * sizeof(bf16_t);   // 32 MB

    if (ws_size >= xb + wb) {
        bf16_t* xbf = (bf16_t*)d_ws;
        bf16_t* wbf = (bf16_t*)((char*)d_ws + xb);

        cvt_f32_to_bf16<<<2048, 256, 0, stream>>>(x, xbf, (M_DIM * K_DIM) / 8);
        cvt_f32_to_bf16<<<1024, 256, 0, stream>>>(w, wbf, (N_DIM * K_DIM) / 8);

        const int grid = (M_DIM / BM) * (N_DIM / BN);   // 32 * 16 = 512
        gemm_bf16_8phase<<<grid, 512, 0, stream>>>(xbf, wbf, bias, out);
    } else {
        dim3 block(16, 16);
        dim3 grid(N_DIM / 16, M_DIM / 16);
        gemm_fallback_f32<<<grid, block, 0, stream>>>(x, w, bias, out);
    }
}